// Round 1
// baseline (1020.593 us; speedup 1.0000x reference)
//
#include <hip/hip_runtime.h>

#define NXg   512
#define NYg   512
#define NTt   400
#define NEh   4
#define DIMg  520            // NXg + 2*NEh
#define DTc   0.001f
#define Hc    10.0f

#define C0f (-205.0f/72.0f)
#define C1f (8.0f/5.0f)
#define C2f (-1.0f/5.0f)
#define C3f (8.0f/315.0f)
#define C4f (-1.0f/560.0f)

// Build scale[] = (vpad*DT)^2/H^2 (with edge-padded, transposed vel) and zero
// both u buffers. Must run every call: harness poisons ws once and never
// re-poisons between timed replays.
__global__ void time2d_init(const float* __restrict__ vel,
                            float* __restrict__ scale,
                            float* __restrict__ uA,
                            float* __restrict__ uB) {
    int idx = blockIdx.x * blockDim.x + threadIdx.x;
    if (idx >= DIMg * DIMg) return;
    int y = idx / DIMg;
    int x = idx - y * DIMg;
    int cy = min(max(y - NEh, 0), NYg - 1);
    int cx = min(max(x - NEh, 0), NXg - 1);
    // vpad[y][x] = vel.T(padded)[y][x] = vel[cx][cy]
    float v = vel[cx * NYg + cy] * DTc;
    scale[idx] = v * v / (Hc * Hc);
    uA[idx] = 0.0f;
    uB[idx] = 0.0f;
}

// One time step: u_next = 2*u_cur - u_prev + scale * lap(u_cur) on the
// interior (halo stays 0 == mask semantics), + source injection, + record
// receiver row into out[t]. u_next may alias u_prev (pointwise read).
__launch_bounds__(256)
__global__ void time2d_step(const float* __restrict__ up,
                            const float* __restrict__ uc,
                            float* __restrict__ un,
                            const float* __restrict__ scale,
                            const float* __restrict__ w,
                            const float* __restrict__ vel,
                            const int* __restrict__ sx_p,
                            const int* __restrict__ sy_p,
                            const int* __restrict__ ry_p,
                            float* __restrict__ out,
                            int t) {
    int x = blockIdx.x * 64 + (threadIdx.x & 63) + NEh;   // 4..515
    int y = blockIdx.y * 4 + (threadIdx.x >> 6) + NEh;    // 4..515
    int idx = y * DIMg + x;

    float c = uc[idx];
    float lap = 2.0f * C0f * c
        + C1f * (uc[idx - 1*DIMg] + uc[idx + 1*DIMg] + uc[idx - 1] + uc[idx + 1])
        + C2f * (uc[idx - 2*DIMg] + uc[idx + 2*DIMg] + uc[idx - 2] + uc[idx + 2])
        + C3f * (uc[idx - 3*DIMg] + uc[idx + 3*DIMg] + uc[idx - 3] + uc[idx + 3])
        + C4f * (uc[idx - 4*DIMg] + uc[idx + 4*DIMg] + uc[idx - 4] + uc[idx + 4]);

    float val = 2.0f * c - up[idx] + scale[idx] * lap;

    int sx = *sx_p, sy = *sy_p, ry = *ry_p;
    if (y == sy + NEh && x == sx + NEh) {
        float va = vel[sx * NYg + sy] * DTc;   // vpad[iy][ix] = vel[sx][sy]
        val += w[t] * (va * va);
    }
    un[idx] = val;

    if (y == ry + NEh) out[t * NXg + (x - NEh)] = val;
}

extern "C" void kernel_launch(void* const* d_in, const int* in_sizes, int n_in,
                              void* d_out, int out_size, void* d_ws, size_t ws_size,
                              hipStream_t stream) {
    const float* vel = (const float*)d_in[0];
    const float* w   = (const float*)d_in[1];
    const int*   sx  = (const int*)d_in[2];
    const int*   sy  = (const int*)d_in[3];
    const int*   ry  = (const int*)d_in[4];
    float* out = (float*)d_out;

    float* ws    = (float*)d_ws;
    float* scale = ws;
    float* uA    = ws + DIMg * DIMg;
    float* uB    = uA + DIMg * DIMg;

    int n = DIMg * DIMg;
    time2d_init<<<(n + 255) / 256, 256, 0, stream>>>(vel, scale, uA, uB);

    // carry (u1, u2) = (uA, uB), both zero.
    float* up = uA;   // u1
    float* uc = uB;   // u2
    dim3 grid(NXg / 64, NYg / 4);
    for (int t = 0; t < NTt; ++t) {
        // u3 -> up's buffer (u1 dead after this step)
        time2d_step<<<grid, 256, 0, stream>>>(up, uc, up, scale, w, vel,
                                              sx, sy, ry, out, t);
        float* tmp = uc; uc = up; up = tmp;   // (u1,u2) <- (u2,u3)
    }
}